// Round 1
// baseline (587.742 us; speedup 1.0000x reference)
//
#include <hip/hip_runtime.h>

typedef unsigned short ushort_t;
using f32x4  = __attribute__((ext_vector_type(4))) float;
using bf16x8 = __attribute__((ext_vector_type(8))) __bf16;

union Frag {
    uint4    u4;
    bf16x8   b;
    ushort_t s[8];
};

__device__ __forceinline__ ushort_t f2bf(float f) {
    union { float f; unsigned u; } a; a.f = f;
    unsigned u = a.u;
    unsigned r = (u + 0x7fffu + ((u >> 16) & 1u)) >> 16;   // RNE
    return (ushort_t)r;
}
__device__ __forceinline__ float bf2f(ushort_t b) {
    union { unsigned u; float f; } a; a.u = ((unsigned)b) << 16;
    return a.f;
}

// ---------------------------------------------------------------- LayerNorm
// one block per row of 1024; fp32 in -> bf16 out
__global__ __launch_bounds__(256)
void ln_kernel(const float* __restrict__ x, const float* __restrict__ gamma,
               ushort_t* __restrict__ xn)
{
    const int row = blockIdx.x;
    const int tid = threadIdx.x;
    const float4 v = *reinterpret_cast<const float4*>(x + (size_t)row * 1024 + tid * 4);

    float s = v.x + v.y + v.z + v.w;
    float q = v.x * v.x + v.y * v.y + v.z * v.z + v.w * v.w;
    #pragma unroll
    for (int off = 1; off <= 32; off <<= 1) {
        s += __shfl_xor(s, off);
        q += __shfl_xor(q, off);
    }
    __shared__ float ss[4], sq[4];
    if ((tid & 63) == 0) { ss[tid >> 6] = s; sq[tid >> 6] = q; }
    __syncthreads();
    const float S  = ss[0] + ss[1] + ss[2] + ss[3];
    const float Q  = sq[0] + sq[1] + sq[2] + sq[3];
    const float mu = S * (1.0f / 1024.0f);
    const float var = Q * (1.0f / 1024.0f) - mu * mu;
    const float rstd = rsqrtf(var + 1e-5f);

    const float4 gm = *reinterpret_cast<const float4*>(gamma + tid * 4);
    ushort4 o;
    o.x = f2bf((v.x - mu) * rstd * gm.x);
    o.y = f2bf((v.y - mu) * rstd * gm.y);
    o.z = f2bf((v.z - mu) * rstd * gm.z);
    o.w = f2bf((v.w - mu) * rstd * gm.w);
    *reinterpret_cast<ushort4*>(xn + (size_t)row * 1024 + tid * 4) = o;
}

// ------------------------------------------- weight transpose fp32[K][N] -> bf16[N][K]
__global__ __launch_bounds__(256)
void wt_kernel(const float* __restrict__ w, ushort_t* __restrict__ wt, int K, int N)
{
    __shared__ float tile[32][33];
    const int n0 = blockIdx.x * 32, k0 = blockIdx.y * 32;
    const int tx = threadIdx.x, ty = threadIdx.y;   // (32, 8)
    #pragma unroll
    for (int i = 0; i < 4; ++i) {
        int r = ty + i * 8;
        tile[r][tx] = w[(size_t)(k0 + r) * N + n0 + tx];
    }
    __syncthreads();
    #pragma unroll
    for (int i = 0; i < 4; ++i) {
        int r = ty + i * 8;
        wt[(size_t)(n0 + r) * K + k0 + tx] = f2bf(tile[tx][r]);
    }
}

// ---------------------------------------------------------------- GEMM
// C[M,N] = A[M,1024](bf16) * Bt[N,1024](bf16)^T ; 128x128 tile, BK=32, 4 waves.
// MODE 0: write q_heads [b,h,n,d] * 0.125    (o16a)
// MODE 1: n<1024 -> k_heads [b,h,n,d] (o16a); n>=1024 -> v_t [b,h,d,n] (o16b)
// MODE 2: write fp32 row-major (o32)
#define LDK 40   // ushorts per LDS row: 32 + 8 pad -> 5 granules, conflict-free

template<int MODE>
__global__ __launch_bounds__(256)
void gemm_kernel(const ushort_t* __restrict__ A, const ushort_t* __restrict__ Bt,
                 ushort_t* __restrict__ o16a, ushort_t* __restrict__ o16b,
                 float* __restrict__ o32)
{
    __shared__ ushort_t ldsA[128 * LDK];
    __shared__ ushort_t ldsB[128 * LDK];

    const int tid = threadIdx.x;
    const int n0 = blockIdx.x * 128, m0 = blockIdx.y * 128;
    const int w = tid >> 6, l = tid & 63, g = l >> 4, c = l & 15;
    const int wm = w >> 1, wn = w & 1;

    const int srow = tid >> 2, skc = tid & 3;
    const ushort_t* ag0 = A  + (size_t)(m0 + srow)      * 1024 + skc * 8;
    const ushort_t* ag1 = A  + (size_t)(m0 + srow + 64) * 1024 + skc * 8;
    const ushort_t* bg0 = Bt + (size_t)(n0 + srow)      * 1024 + skc * 8;
    const ushort_t* bg1 = Bt + (size_t)(n0 + srow + 64) * 1024 + skc * 8;
    const int l0 = srow * LDK + skc * 8;
    const int l1 = (srow + 64) * LDK + skc * 8;

    f32x4 acc[4][4];
    #pragma unroll
    for (int mi = 0; mi < 4; ++mi)
        #pragma unroll
        for (int ni = 0; ni < 4; ++ni)
            acc[mi][ni] = (f32x4){0.f, 0.f, 0.f, 0.f};

    for (int kt = 0; kt < 32; ++kt) {
        const int ko = kt * 32;
        uint4 a0 = *reinterpret_cast<const uint4*>(ag0 + ko);
        uint4 a1 = *reinterpret_cast<const uint4*>(ag1 + ko);
        uint4 b0 = *reinterpret_cast<const uint4*>(bg0 + ko);
        uint4 b1 = *reinterpret_cast<const uint4*>(bg1 + ko);
        __syncthreads();                // previous tile's reads done
        *reinterpret_cast<uint4*>(&ldsA[l0]) = a0;
        *reinterpret_cast<uint4*>(&ldsA[l1]) = a1;
        *reinterpret_cast<uint4*>(&ldsB[l0]) = b0;
        *reinterpret_cast<uint4*>(&ldsB[l1]) = b1;
        __syncthreads();                // writes visible

        Frag af[4], bfr[4];
        #pragma unroll
        for (int mi = 0; mi < 4; ++mi)
            af[mi].u4 = *reinterpret_cast<const uint4*>(&ldsA[(wm * 64 + mi * 16 + c) * LDK + g * 8]);
        #pragma unroll
        for (int ni = 0; ni < 4; ++ni)
            bfr[ni].u4 = *reinterpret_cast<const uint4*>(&ldsB[(wn * 64 + ni * 16 + c) * LDK + g * 8]);
        #pragma unroll
        for (int mi = 0; mi < 4; ++mi)
            #pragma unroll
            for (int ni = 0; ni < 4; ++ni)
                acc[mi][ni] = __builtin_amdgcn_mfma_f32_16x16x32_bf16(
                    af[mi].b, bfr[ni].b, acc[mi][ni], 0, 0, 0);
    }

    // epilogue:  m = mbase + r (rows), n = col;  D layout: row=(l>>4)*4+r, col=l&15
    #pragma unroll
    for (int mi = 0; mi < 4; ++mi) {
        const int mbase = m0 + wm * 64 + mi * 16 + g * 4;
        #pragma unroll
        for (int ni = 0; ni < 4; ++ni) {
            const int n = n0 + wn * 64 + ni * 16 + c;
            if (MODE == 0) {
                const int hh = n >> 6, d = n & 63;
                #pragma unroll
                for (int r = 0; r < 4; ++r) {
                    const int m = mbase + r;
                    const int b = m >> 11, tok = m & 2047;
                    o16a[(((size_t)b * 16 + hh) * 2048 + tok) * 64 + d] =
                        f2bf(acc[mi][ni][r] * 0.125f);
                }
            } else if (MODE == 1) {
                if (n < 1024) {
                    const int hh = n >> 6, d = n & 63;
                    #pragma unroll
                    for (int r = 0; r < 4; ++r) {
                        const int m = mbase + r;
                        const int b = m >> 11, tok = m & 2047;
                        o16a[(((size_t)b * 16 + hh) * 2048 + tok) * 64 + d] =
                            f2bf(acc[mi][ni][r]);
                    }
                } else {
                    const int nn = n - 1024;
                    const int hh = nn >> 6, d = nn & 63;
                    const int b = mbase >> 11, tok0 = mbase & 2047;
                    ushort4 pv;
                    pv.x = f2bf(acc[mi][ni][0]);
                    pv.y = f2bf(acc[mi][ni][1]);
                    pv.z = f2bf(acc[mi][ni][2]);
                    pv.w = f2bf(acc[mi][ni][3]);
                    *reinterpret_cast<ushort4*>(
                        o16b + (((size_t)b * 16 + hh) * 64 + d) * 2048 + tok0) = pv;
                }
            } else {
                #pragma unroll
                for (int r = 0; r < 4; ++r)
                    o32[(size_t)(mbase + r) * 1024 + n] = acc[mi][ni][r];
            }
        }
    }
}

// ---------------------------------------------------------------- flash attention
// grid (32 qblocks, 64 bh); 4 waves/block, wave owns 16 q-rows; KVBLK=64.
// null kv handled analytically in the online-softmax init.
__global__ __launch_bounds__(256)
void attn_kernel(const ushort_t* __restrict__ q, const ushort_t* __restrict__ k,
                 const ushort_t* __restrict__ vt, const float* __restrict__ nkv,
                 ushort_t* __restrict__ out)
{
    __shared__ ushort_t plds[4][16 * 72];   // per-wave P buffer, 72 = 64 + 8 pad
    const int tid = threadIdx.x;
    const int w = tid >> 6, l = tid & 63, g = l >> 4, c = l & 15;
    const int qb = blockIdx.x, bh = blockIdx.y, h = bh & 15;

    // Q fragments: lane holds Q[row=c][k = kk*32 + g*8 + i]  (q pre-scaled by 0.125)
    const ushort_t* qbase = q + ((size_t)bh * 2048 + qb * 64 + w * 16) * 64;
    Frag aq[2];
    #pragma unroll
    for (int kk = 0; kk < 2; ++kk)
        aq[kk].u4 = *reinterpret_cast<const uint4*>(qbase + c * 64 + kk * 32 + g * 8);

    // s_null[row=c] = q_row . null_k
    float snull = 0.f;
    #pragma unroll
    for (int kk = 0; kk < 2; ++kk) {
        const float4 n0 = *reinterpret_cast<const float4*>(nkv + h * 64 + kk * 32 + g * 8);
        const float4 n1 = *reinterpret_cast<const float4*>(nkv + h * 64 + kk * 32 + g * 8 + 4);
        snull += bf2f(aq[kk].s[0]) * n0.x + bf2f(aq[kk].s[1]) * n0.y
               + bf2f(aq[kk].s[2]) * n0.z + bf2f(aq[kk].s[3]) * n0.w;
        snull += bf2f(aq[kk].s[4]) * n1.x + bf2f(aq[kk].s[5]) * n1.y
               + bf2f(aq[kk].s[6]) * n1.z + bf2f(aq[kk].s[7]) * n1.w;
    }
    snull += __shfl_xor(snull, 16);
    snull += __shfl_xor(snull, 32);

    // online-softmax state for this lane's acc rows (q = g*4 + r)
    float m_run[4], l_run[4];
    f32x4 acc[4];                 // O[q = g*4+r][d = nf*16 + c]
    #pragma unroll
    for (int r = 0; r < 4; ++r) {
        m_run[r] = __shfl(snull, g * 4 + r);
        l_run[r] = 1.f;
    }
    #pragma unroll
    for (int nf = 0; nf < 4; ++nf) {
        const float nv = nkv[1024 + h * 64 + nf * 16 + c];
        #pragma unroll
        for (int r = 0; r < 4; ++r) acc[nf][r] = nv;   // exp(snull - m)=1 times nv
    }

    const ushort_t* kb = k  + (size_t)bh * 2048 * 64;
    const ushort_t* vb = vt + (size_t)bh * 64 * 2048;
    ushort_t* pw = &plds[w][0];

    for (int t = 0; t < 32; ++t) {
        // K fragments: lane holds K[kv = t*64+nt*16+c][d = kk*32+g*8+i]
        Frag bk[4][2];
        #pragma unroll
        for (int nt = 0; nt < 4; ++nt)
            #pragma unroll
            for (int kk = 0; kk < 2; ++kk)
                bk[nt][kk].u4 = *reinterpret_cast<const uint4*>(
                    kb + (size_t)(t * 64 + nt * 16 + c) * 64 + kk * 32 + g * 8);

        // S[q][kv]: lane holds rows q=g*4+r, col kv = nt*16 + c
        f32x4 s[4];
        #pragma unroll
        for (int nt = 0; nt < 4; ++nt) {
            f32x4 z = (f32x4){0.f, 0.f, 0.f, 0.f};
            s[nt] = __builtin_amdgcn_mfma_f32_16x16x32_bf16(aq[0].b, bk[nt][0].b, z, 0, 0, 0);
            s[nt] = __builtin_amdgcn_mfma_f32_16x16x32_bf16(aq[1].b, bk[nt][1].b, s[nt], 0, 0, 0);
        }

        // online softmax
        float nm[4], alpha[4];
        #pragma unroll
        for (int r = 0; r < 4; ++r) {
            float tm = fmaxf(fmaxf(s[0][r], s[1][r]), fmaxf(s[2][r], s[3][r]));
            tm = fmaxf(tm, __shfl_xor(tm, 1));
            tm = fmaxf(tm, __shfl_xor(tm, 2));
            tm = fmaxf(tm, __shfl_xor(tm, 4));
            tm = fmaxf(tm, __shfl_xor(tm, 8));
            nm[r] = fmaxf(m_run[r], tm);
            alpha[r] = __expf(m_run[r] - nm[r]);
            m_run[r] = nm[r];
        }
        #pragma unroll
        for (int nt = 0; nt < 4; ++nt)
            #pragma unroll
            for (int r = 0; r < 4; ++r)
                s[nt][r] = __expf(s[nt][r] - nm[r]);
        #pragma unroll
        for (int r = 0; r < 4; ++r) {
            float ts = s[0][r] + s[1][r] + s[2][r] + s[3][r];
            ts += __shfl_xor(ts, 1);
            ts += __shfl_xor(ts, 2);
            ts += __shfl_xor(ts, 4);
            ts += __shfl_xor(ts, 8);
            l_run[r] = l_run[r] * alpha[r] + ts;
        }
        #pragma unroll
        for (int nf = 0; nf < 4; ++nf)
            #pragma unroll
            for (int r = 0; r < 4; ++r)
                acc[nf][r] *= alpha[r];

        // P -> LDS (transpose within wave-private buffer), then A-fragments
        #pragma unroll
        for (int nt = 0; nt < 4; ++nt)
            #pragma unroll
            for (int r = 0; r < 4; ++r)
                pw[(g * 4 + r) * 72 + nt * 16 + c] = f2bf(s[nt][r]);

        Frag pa[2];
        #pragma unroll
        for (int k2 = 0; k2 < 2; ++k2)
            pa[k2].u4 = *reinterpret_cast<const uint4*>(&pw[c * 72 + k2 * 32 + g * 8]);

        // V fragments from v_t[b,h,d,n]: lane holds V[kv = k2*32+g*8+i][d = nf*16+c]
        Frag bv[4][2];
        #pragma unroll
        for (int nf = 0; nf < 4; ++nf)
            #pragma unroll
            for (int k2 = 0; k2 < 2; ++k2)
                bv[nf][k2].u4 = *reinterpret_cast<const uint4*>(
                    vb + (size_t)(nf * 16 + c) * 2048 + t * 64 + k2 * 32 + g * 8);

        #pragma unroll
        for (int nf = 0; nf < 4; ++nf) {
            acc[nf] = __builtin_amdgcn_mfma_f32_16x16x32_bf16(pa[0].b, bv[nf][0].b, acc[nf], 0, 0, 0);
            acc[nf] = __builtin_amdgcn_mfma_f32_16x16x32_bf16(pa[1].b, bv[nf][1].b, acc[nf], 0, 0, 0);
        }
    }

    // normalize + store to attn_out [b, tok, h*64+d] (bf16)
    const size_t ob = ((size_t)(bh >> 4) * 2048 + qb * 64 + w * 16) * 1024 + h * 64;
    #pragma unroll
    for (int r = 0; r < 4; ++r) {
        const float inv = 1.f / l_run[r];
        #pragma unroll
        for (int nf = 0; nf < 4; ++nf)
            out[ob + (size_t)(g * 4 + r) * 1024 + nf * 16 + c] = f2bf(acc[nf][r] * inv);
    }
}

// ---------------------------------------------------------------- launch
extern "C" void kernel_launch(void* const* d_in, const int* in_sizes, int n_in,
                              void* d_out, int out_size, void* d_ws, size_t ws_size,
                              hipStream_t stream)
{
    (void)in_sizes; (void)n_in; (void)out_size; (void)ws_size;
    const float* x     = (const float*)d_in[0];
    const float* gamma = (const float*)d_in[1];
    const float* w_q   = (const float*)d_in[2];
    const float* w_kv  = (const float*)d_in[3];
    const float* w_out = (const float*)d_in[4];
    const float* nkv   = (const float*)d_in[5];
    float* out = (float*)d_out;

    char* ws = (char*)d_ws;
    ushort_t* xn   = (ushort_t*)(ws);               // 16 MB  [8192,1024] bf16
    ushort_t* wqT  = (ushort_t*)(ws + 16777216);    //  2 MB  [1024,1024]
    ushort_t* wkvT = (ushort_t*)(ws + 18874368);    //  4 MB  [2048,1024]
    ushort_t* woT  = (ushort_t*)(ws + 23068672);    //  2 MB  [1024,1024]
    ushort_t* qh   = (ushort_t*)(ws + 25165824);    // 16 MB  [b,h,2048,64]
    ushort_t* kh   = (ushort_t*)(ws + 41943040);    // 16 MB  [b,h,2048,64]
    ushort_t* vtb  = (ushort_t*)(ws + 58720256);    // 16 MB  [b,h,64,2048]
    ushort_t* ao   = xn;                            // attn output reuses xn

    ln_kernel<<<dim3(8192), dim3(256), 0, stream>>>(x, gamma, xn);
    wt_kernel<<<dim3(32, 32), dim3(32, 8), 0, stream>>>(w_q,  wqT, 1024, 1024);
    wt_kernel<<<dim3(64, 32), dim3(32, 8), 0, stream>>>(w_kv, wkvT, 1024, 2048);
    wt_kernel<<<dim3(32, 32), dim3(32, 8), 0, stream>>>(w_out, woT, 1024, 1024);

    gemm_kernel<0><<<dim3(8, 64),  dim3(256), 0, stream>>>(xn, wqT,  qh, nullptr, nullptr);
    gemm_kernel<1><<<dim3(16, 64), dim3(256), 0, stream>>>(xn, wkvT, kh, vtb, nullptr);

    attn_kernel<<<dim3(32, 64), dim3(256), 0, stream>>>(qh, kh, vtb, nkv, ao);

    gemm_kernel<2><<<dim3(8, 64), dim3(256), 0, stream>>>(ao, woT, nullptr, nullptr, out);
}

// Round 2
// 586.990 us; speedup vs baseline: 1.0013x; 1.0013x over previous
//
#include <hip/hip_runtime.h>

typedef unsigned short ushort_t;
using f32x4  = __attribute__((ext_vector_type(4))) float;
using bf16x8 = __attribute__((ext_vector_type(8))) __bf16;

union Frag {
    uint4    u4;
    bf16x8   b;
    ushort_t s[8];
};

__device__ __forceinline__ ushort_t f2bf(float f) {
    union { float f; unsigned u; } a; a.f = f;
    unsigned u = a.u;
    unsigned r = (u + 0x7fffu + ((u >> 16) & 1u)) >> 16;   // RNE
    return (ushort_t)r;
}
__device__ __forceinline__ float bf2f(ushort_t b) {
    union { unsigned u; float f; } a; a.u = ((unsigned)b) << 16;
    return a.f;
}
__device__ __forceinline__ unsigned pack2bf(float lo, float hi) {
    union { __bf16 h[2]; unsigned u; } p;
    p.h[0] = (__bf16)lo;
    p.h[1] = (__bf16)hi;
    return p.u;
}

// ---------------------------------------------------------------- LayerNorm
__global__ __launch_bounds__(256)
void ln_kernel(const float* __restrict__ x, const float* __restrict__ gamma,
               ushort_t* __restrict__ xn)
{
    const int row = blockIdx.x;
    const int tid = threadIdx.x;
    const float4 v = *reinterpret_cast<const float4*>(x + (size_t)row * 1024 + tid * 4);

    float s = v.x + v.y + v.z + v.w;
    float q = v.x * v.x + v.y * v.y + v.z * v.z + v.w * v.w;
    #pragma unroll
    for (int off = 1; off <= 32; off <<= 1) {
        s += __shfl_xor(s, off);
        q += __shfl_xor(q, off);
    }
    __shared__ float ss[4], sq[4];
    if ((tid & 63) == 0) { ss[tid >> 6] = s; sq[tid >> 6] = q; }
    __syncthreads();
    const float S  = ss[0] + ss[1] + ss[2] + ss[3];
    const float Q  = sq[0] + sq[1] + sq[2] + sq[3];
    const float mu = S * (1.0f / 1024.0f);
    const float var = Q * (1.0f / 1024.0f) - mu * mu;
    const float rstd = rsqrtf(var + 1e-5f);

    const float4 gm = *reinterpret_cast<const float4*>(gamma + tid * 4);
    ushort4 o;
    o.x = f2bf((v.x - mu) * rstd * gm.x);
    o.y = f2bf((v.y - mu) * rstd * gm.y);
    o.z = f2bf((v.z - mu) * rstd * gm.z);
    o.w = f2bf((v.w - mu) * rstd * gm.w);
    *reinterpret_cast<ushort4*>(xn + (size_t)row * 1024 + tid * 4) = o;
}

// ------------------------------------------- weight transpose fp32[K][N] -> bf16[N][K]
__global__ __launch_bounds__(256)
void wt_kernel(const float* __restrict__ w, ushort_t* __restrict__ wt, int K, int N)
{
    __shared__ float tile[32][33];
    const int n0 = blockIdx.x * 32, k0 = blockIdx.y * 32;
    const int tx = threadIdx.x, ty = threadIdx.y;   // (32, 8)
    #pragma unroll
    for (int i = 0; i < 4; ++i) {
        int r = ty + i * 8;
        tile[r][tx] = w[(size_t)(k0 + r) * N + n0 + tx];
    }
    __syncthreads();
    #pragma unroll
    for (int i = 0; i < 4; ++i) {
        int r = ty + i * 8;
        wt[(size_t)(n0 + r) * K + k0 + tx] = f2bf(tile[tx][r]);
    }
}

// ---------------------------------------------------------------- GEMM
#define LDK 40   // ushorts per LDS row: 32 + 8 pad

template<int MODE>
__global__ __launch_bounds__(256)
void gemm_kernel(const ushort_t* __restrict__ A, const ushort_t* __restrict__ Bt,
                 ushort_t* __restrict__ o16a, ushort_t* __restrict__ o16b,
                 float* __restrict__ o32)
{
    __shared__ ushort_t ldsA[128 * LDK];
    __shared__ ushort_t ldsB[128 * LDK];

    const int tid = threadIdx.x;
    const int n0 = blockIdx.x * 128, m0 = blockIdx.y * 128;
    const int w = tid >> 6, l = tid & 63, g = l >> 4, c = l & 15;
    const int wm = w >> 1, wn = w & 1;

    const int srow = tid >> 2, skc = tid & 3;
    const ushort_t* ag0 = A  + (size_t)(m0 + srow)      * 1024 + skc * 8;
    const ushort_t* ag1 = A  + (size_t)(m0 + srow + 64) * 1024 + skc * 8;
    const ushort_t* bg0 = Bt + (size_t)(n0 + srow)      * 1024 + skc * 8;
    const ushort_t* bg1 = Bt + (size_t)(n0 + srow + 64) * 1024 + skc * 8;
    const int l0 = srow * LDK + skc * 8;
    const int l1 = (srow + 64) * LDK + skc * 8;

    f32x4 acc[4][4];
    #pragma unroll
    for (int mi = 0; mi < 4; ++mi)
        #pragma unroll
        for (int ni = 0; ni < 4; ++ni)
            acc[mi][ni] = (f32x4){0.f, 0.f, 0.f, 0.f};

    for (int kt = 0; kt < 32; ++kt) {
        const int ko = kt * 32;
        uint4 a0 = *reinterpret_cast<const uint4*>(ag0 + ko);
        uint4 a1 = *reinterpret_cast<const uint4*>(ag1 + ko);
        uint4 b0 = *reinterpret_cast<const uint4*>(bg0 + ko);
        uint4 b1 = *reinterpret_cast<const uint4*>(bg1 + ko);
        __syncthreads();
        *reinterpret_cast<uint4*>(&ldsA[l0]) = a0;
        *reinterpret_cast<uint4*>(&ldsA[l1]) = a1;
        *reinterpret_cast<uint4*>(&ldsB[l0]) = b0;
        *reinterpret_cast<uint4*>(&ldsB[l1]) = b1;
        __syncthreads();

        Frag af[4], bfr[4];
        #pragma unroll
        for (int mi = 0; mi < 4; ++mi)
            af[mi].u4 = *reinterpret_cast<const uint4*>(&ldsA[(wm * 64 + mi * 16 + c) * LDK + g * 8]);
        #pragma unroll
        for (int ni = 0; ni < 4; ++ni)
            bfr[ni].u4 = *reinterpret_cast<const uint4*>(&ldsB[(wn * 64 + ni * 16 + c) * LDK + g * 8]);
        #pragma unroll
        for (int mi = 0; mi < 4; ++mi)
            #pragma unroll
            for (int ni = 0; ni < 4; ++ni)
                acc[mi][ni] = __builtin_amdgcn_mfma_f32_16x16x32_bf16(
                    af[mi].b, bfr[ni].b, acc[mi][ni], 0, 0, 0);
    }

    #pragma unroll
    for (int mi = 0; mi < 4; ++mi) {
        const int mbase = m0 + wm * 64 + mi * 16 + g * 4;
        #pragma unroll
        for (int ni = 0; ni < 4; ++ni) {
            const int n = n0 + wn * 64 + ni * 16 + c;
            if (MODE == 0) {
                const int hh = n >> 6, d = n & 63;
                #pragma unroll
                for (int r = 0; r < 4; ++r) {
                    const int m = mbase + r;
                    const int b = m >> 11, tok = m & 2047;
                    o16a[(((size_t)b * 16 + hh) * 2048 + tok) * 64 + d] =
                        f2bf(acc[mi][ni][r] * 0.125f);
                }
            } else if (MODE == 1) {
                if (n < 1024) {
                    const int hh = n >> 6, d = n & 63;
                    #pragma unroll
                    for (int r = 0; r < 4; ++r) {
                        const int m = mbase + r;
                        const int b = m >> 11, tok = m & 2047;
                        o16a[(((size_t)b * 16 + hh) * 2048 + tok) * 64 + d] =
                            f2bf(acc[mi][ni][r]);
                    }
                } else {
                    const int nn = n - 1024;
                    const int hh = nn >> 6, d = nn & 63;
                    const int b = mbase >> 11, tok0 = mbase & 2047;
                    ushort4 pv;
                    pv.x = f2bf(acc[mi][ni][0]);
                    pv.y = f2bf(acc[mi][ni][1]);
                    pv.z = f2bf(acc[mi][ni][2]);
                    pv.w = f2bf(acc[mi][ni][3]);
                    *reinterpret_cast<ushort4*>(
                        o16b + (((size_t)b * 16 + hh) * 64 + d) * 2048 + tok0) = pv;
                }
            } else {
                #pragma unroll
                for (int r = 0; r < 4; ++r)
                    o32[(size_t)(mbase + r) * 1024 + n] = acc[mi][ni][r];
            }
        }
    }
}

// ---------------------------------------------------------------- flash attention v2
// grid (32 qblocks, 64 bh); 4 waves/block, wave owns 16 q-rows; KVBLK=64.
// Swapped QK^T: S^T = mfma(A=K, B=Q) -> lane holds a full slice of ONE q-row
// (q = lane&15), so row max/sum are in-lane + 2 shuffles. Defer-max (T13).
__global__ __launch_bounds__(256)
void attn_kernel(const ushort_t* __restrict__ q, const ushort_t* __restrict__ k,
                 const ushort_t* __restrict__ vt, const float* __restrict__ nkv,
                 ushort_t* __restrict__ out)
{
    __shared__ ushort_t plds[4][16 * 72];   // per-wave P buffer [q=16][kv=64+8pad]
    const int tid = threadIdx.x;
    const int w = tid >> 6, l = tid & 63, g = l >> 4, c = l & 15;
    const int qb = blockIdx.x, bh = blockIdx.y, h = bh & 15;

    // Q fragments: lane holds Q[row=c][d = kk*32 + g*8 + i]  (q pre-scaled by 0.125)
    const ushort_t* qbase = q + ((size_t)bh * 2048 + qb * 64 + w * 16) * 64;
    Frag aq[2];
    #pragma unroll
    for (int kk = 0; kk < 2; ++kk)
        aq[kk].u4 = *reinterpret_cast<const uint4*>(qbase + c * 64 + kk * 32 + g * 8);

    // snull = q_row(c) . null_k  — reduce across the 4 g-copies
    float snull = 0.f;
    #pragma unroll
    for (int kk = 0; kk < 2; ++kk) {
        const float4 n0 = *reinterpret_cast<const float4*>(nkv + h * 64 + kk * 32 + g * 8);
        const float4 n1 = *reinterpret_cast<const float4*>(nkv + h * 64 + kk * 32 + g * 8 + 4);
        snull += bf2f(aq[kk].s[0]) * n0.x + bf2f(aq[kk].s[1]) * n0.y
               + bf2f(aq[kk].s[2]) * n0.z + bf2f(aq[kk].s[3]) * n0.w;
        snull += bf2f(aq[kk].s[4]) * n1.x + bf2f(aq[kk].s[5]) * n1.y
               + bf2f(aq[kk].s[6]) * n1.z + bf2f(aq[kk].s[7]) * n1.w;
    }
    snull += __shfl_xor(snull, 16);
    snull += __shfl_xor(snull, 32);

    // per-lane online-softmax state for q-row = c
    float m_run = snull;
    float l_run = 1.f;

    // acc: O[q = g*4+r][d = nf*16+c] ; init with null_v (exp(snull-m)=1)
    f32x4 acc[4];
    #pragma unroll
    for (int nf = 0; nf < 4; ++nf) {
        const float nv = nkv[1024 + h * 64 + nf * 16 + c];
        #pragma unroll
        for (int r = 0; r < 4; ++r) acc[nf][r] = nv;
    }

    const ushort_t* kb = k  + (size_t)bh * 2048 * 64;
    const ushort_t* vb = vt + (size_t)bh * 64 * 2048;
    ushort_t* pw = &plds[w][0];

    for (int t = 0; t < 32; ++t) {
        // K as A-fragment: lane holds K[kv_local = nt*16 + c][d = kk*32 + g*8 + i]
        Frag bk[4][2];
        #pragma unroll
        for (int nt = 0; nt < 4; ++nt)
            #pragma unroll
            for (int kk = 0; kk < 2; ++kk)
                bk[nt][kk].u4 = *reinterpret_cast<const uint4*>(
                    kb + (size_t)(t * 64 + nt * 16 + c) * 64 + kk * 32 + g * 8);

        // S^T[kv][q]: lane holds q = c, kv_local = nt*16 + g*4 + r
        f32x4 st[4];
        #pragma unroll
        for (int nt = 0; nt < 4; ++nt) {
            f32x4 z = (f32x4){0.f, 0.f, 0.f, 0.f};
            st[nt] = __builtin_amdgcn_mfma_f32_16x16x32_bf16(bk[nt][0].b, aq[0].b, z, 0, 0, 0);
            st[nt] = __builtin_amdgcn_mfma_f32_16x16x32_bf16(bk[nt][1].b, aq[1].b, st[nt], 0, 0, 0);
        }

        // V fragments (independent of softmax — issue early to hide latency)
        Frag bv[4][2];
        #pragma unroll
        for (int nf = 0; nf < 4; ++nf)
            #pragma unroll
            for (int k2 = 0; k2 < 2; ++k2)
                bv[nf][k2].u4 = *reinterpret_cast<const uint4*>(
                    vb + (size_t)(nf * 16 + c) * 2048 + t * 64 + k2 * 32 + g * 8);

        // ---- softmax, fully in-lane for q-row c ----
        float m01 = fmaxf(fmaxf(st[0][0], st[0][1]), fmaxf(st[0][2], st[0][3]));
        float m23 = fmaxf(fmaxf(st[1][0], st[1][1]), fmaxf(st[1][2], st[1][3]));
        float m45 = fmaxf(fmaxf(st[2][0], st[2][1]), fmaxf(st[2][2], st[2][3]));
        float m67 = fmaxf(fmaxf(st[3][0], st[3][1]), fmaxf(st[3][2], st[3][3]));
        float pm = fmaxf(fmaxf(m01, m23), fmaxf(m45, m67));
        pm = fmaxf(pm, __shfl_xor(pm, 16));
        pm = fmaxf(pm, __shfl_xor(pm, 32));

        if (__any(pm > m_run + 8.f)) {      // T13 defer-max
            const float nm = fmaxf(m_run, pm);
            const float alpha = __expf(m_run - nm);
            m_run = nm;
            l_run *= alpha;
            float av[4];
            #pragma unroll
            for (int r = 0; r < 4; ++r) av[r] = __shfl(alpha, g * 4 + r);
            #pragma unroll
            for (int nf = 0; nf < 4; ++nf)
                #pragma unroll
                for (int r = 0; r < 4; ++r)
                    acc[nf][r] *= av[r];
        }

        #pragma unroll
        for (int nt = 0; nt < 4; ++nt)
            #pragma unroll
            for (int r = 0; r < 4; ++r)
                st[nt][r] = __expf(st[nt][r] - m_run);

        float s0 = (st[0][0] + st[0][1]) + (st[0][2] + st[0][3]);
        float s1 = (st[1][0] + st[1][1]) + (st[1][2] + st[1][3]);
        float s2 = (st[2][0] + st[2][1]) + (st[2][2] + st[2][3]);
        float s3 = (st[3][0] + st[3][1]) + (st[3][2] + st[3][3]);
        float ts = (s0 + s1) + (s2 + s3);
        ts += __shfl_xor(ts, 16);
        ts += __shfl_xor(ts, 32);
        l_run += ts;

        // ---- P -> LDS rows [q=c][kv], packed pairs (8x ds_write_b32) ----
        #pragma unroll
        for (int nt = 0; nt < 4; ++nt)
            #pragma unroll
            for (int j = 0; j < 2; ++j)
                *reinterpret_cast<unsigned*>(&pw[c * 72 + nt * 16 + g * 4 + 2 * j]) =
                    pack2bf(st[nt][2 * j], st[nt][2 * j + 1]);

        Frag pa[2];
        #pragma unroll
        for (int k2 = 0; k2 < 2; ++k2)
            pa[k2].u4 = *reinterpret_cast<const uint4*>(&pw[c * 72 + k2 * 32 + g * 8]);

        #pragma unroll
        for (int nf = 0; nf < 4; ++nf) {
            acc[nf] = __builtin_amdgcn_mfma_f32_16x16x32_bf16(pa[0].b, bv[nf][0].b, acc[nf], 0, 0, 0);
            acc[nf] = __builtin_amdgcn_mfma_f32_16x16x32_bf16(pa[1].b, bv[nf][1].b, acc[nf], 0, 0, 0);
        }
    }

    // normalize + store: O rows q = g*4+r need 1/l from lane (q)
    const size_t ob = ((size_t)(bh >> 4) * 2048 + qb * 64 + w * 16) * 1024 + h * 64;
    #pragma unroll
    for (int r = 0; r < 4; ++r) {
        const float inv = 1.f / __shfl(l_run, g * 4 + r);
        #pragma unroll
        for (int nf = 0; nf < 4; ++nf)
            out[ob + (size_t)(g * 4 + r) * 1024 + nf * 16 + c] = f2bf(acc[nf][r] * inv);
    }
}

// ---------------------------------------------------------------- launch
extern "C" void kernel_launch(void* const* d_in, const int* in_sizes, int n_in,
                              void* d_out, int out_size, void* d_ws, size_t ws_size,
                              hipStream_t stream)
{
    (void)in_sizes; (void)n_in; (void)out_size; (void)ws_size;
    const float* x     = (const float*)d_in[0];
    const float* gamma = (const float*)d_in[1];
    const float* w_q   = (const float*)d_in[2];
    const float* w_kv  = (const float*)d_in[3];
    const float* w_out = (const float*)d_in[4];
    const float* nkv   = (const float*)d_in[5];
    float* out = (float*)d_out;

    char* ws = (char*)d_ws;
    ushort_t* xn   = (ushort_t*)(ws);               // 16 MB  [8192,1024] bf16
    ushort_t* wqT  = (ushort_t*)(ws + 16777216);    //  2 MB  [1024,1024]
    ushort_t* wkvT = (ushort_t*)(ws + 18874368);    //  4 MB  [2048,1024]
    ushort_t* woT  = (ushort_t*)(ws + 23068672);    //  2 MB  [1024,1024]
    ushort_t* qh   = (ushort_t*)(ws + 25165824);    // 16 MB  [b,h,2048,64]
    ushort_t* kh   = (ushort_t*)(ws + 41943040);    // 16 MB  [b,h,2048,64]
    ushort_t* vtb  = (ushort_t*)(ws + 58720256);    // 16 MB  [b,h,64,2048]
    ushort_t* ao   = xn;                            // attn output reuses xn

    ln_kernel<<<dim3(8192), dim3(256), 0, stream>>>(x, gamma, xn);
    wt_kernel<<<dim3(32, 32), dim3(32, 8), 0, stream>>>(w_q,  wqT, 1024, 1024);
    wt_kernel<<<dim3(64, 32), dim3(32, 8), 0, stream>>>(w_kv, wkvT, 1024, 2048);
    wt_kernel<<<dim3(32, 32), dim3(32, 8), 0, stream>>>(w_out, woT, 1024, 1024);

    gemm_kernel<0><<<dim3(8, 64),  dim3(256), 0, stream>>>(xn, wqT,  qh, nullptr, nullptr);
    gemm_kernel<1><<<dim3(16, 64), dim3(256), 0, stream>>>(xn, wkvT, kh, vtb, nullptr);

    attn_kernel<<<dim3(32, 64), dim3(256), 0, stream>>>(qh, kh, vtb, nkv, ao);

    gemm_kernel<2><<<dim3(8, 64), dim3(256), 0, stream>>>(ao, woT, nullptr, nullptr, out);
}

// Round 3
// 257.990 us; speedup vs baseline: 2.2782x; 2.2752x over previous
//
#include <hip/hip_runtime.h>

typedef unsigned short ushort_t;
using f32x4  = __attribute__((ext_vector_type(4))) float;
using bf16x8 = __attribute__((ext_vector_type(8))) __bf16;

typedef __attribute__((address_space(1))) const void gvoid_t;
typedef __attribute__((address_space(3))) void svoid_t;

union Frag {
    uint4    u4;
    bf16x8   b;
    ushort_t s[8];
};

__device__ __forceinline__ ushort_t f2bf(float f) {
    union { float f; unsigned u; } a; a.f = f;
    unsigned u = a.u;
    unsigned r = (u + 0x7fffu + ((u >> 16) & 1u)) >> 16;   // RNE
    return (ushort_t)r;
}
__device__ __forceinline__ float bf2f(ushort_t b) {
    union { unsigned u; float f; } a; a.u = ((unsigned)b) << 16;
    return a.f;
}
__device__ __forceinline__ unsigned pack2bf(float lo, float hi) {
    union { __bf16 h[2]; unsigned u; } p;
    p.h[0] = (__bf16)lo;
    p.h[1] = (__bf16)hi;
    return p.u;
}

// ---------------------------------------------------------------- LayerNorm
__global__ __launch_bounds__(256)
void ln_kernel(const float* __restrict__ x, const float* __restrict__ gamma,
               ushort_t* __restrict__ xn)
{
    const int row = blockIdx.x;
    const int tid = threadIdx.x;
    const float4 v = *reinterpret_cast<const float4*>(x + (size_t)row * 1024 + tid * 4);

    float s = v.x + v.y + v.z + v.w;
    float q = v.x * v.x + v.y * v.y + v.z * v.z + v.w * v.w;
    #pragma unroll
    for (int off = 1; off <= 32; off <<= 1) {
        s += __shfl_xor(s, off);
        q += __shfl_xor(q, off);
    }
    __shared__ float ss[4], sq[4];
    if ((tid & 63) == 0) { ss[tid >> 6] = s; sq[tid >> 6] = q; }
    __syncthreads();
    const float S  = ss[0] + ss[1] + ss[2] + ss[3];
    const float Q  = sq[0] + sq[1] + sq[2] + sq[3];
    const float mu = S * (1.0f / 1024.0f);
    const float var = Q * (1.0f / 1024.0f) - mu * mu;
    const float rstd = rsqrtf(var + 1e-5f);

    const float4 gm = *reinterpret_cast<const float4*>(gamma + tid * 4);
    ushort4 o;
    o.x = f2bf((v.x - mu) * rstd * gm.x);
    o.y = f2bf((v.y - mu) * rstd * gm.y);
    o.z = f2bf((v.z - mu) * rstd * gm.z);
    o.w = f2bf((v.w - mu) * rstd * gm.w);
    *reinterpret_cast<ushort4*>(xn + (size_t)row * 1024 + tid * 4) = o;
}

// ------------------------------------------- weight transpose fp32[K][N] -> bf16[N][K]
__global__ __launch_bounds__(256)
void wt_kernel(const float* __restrict__ w, ushort_t* __restrict__ wt, int K, int N)
{
    __shared__ float tile[32][33];
    const int n0 = blockIdx.x * 32, k0 = blockIdx.y * 32;
    const int tx = threadIdx.x, ty = threadIdx.y;   // (32, 8)
    #pragma unroll
    for (int i = 0; i < 4; ++i) {
        int r = ty + i * 8;
        tile[r][tx] = w[(size_t)(k0 + r) * N + n0 + tx];
    }
    __syncthreads();
    #pragma unroll
    for (int i = 0; i < 4; ++i) {
        int r = ty + i * 8;
        wt[(size_t)(n0 + r) * K + k0 + tx] = f2bf(tile[tx][r]);
    }
}

// ---------------------------------------------------------------- GEMM
#define LDK 40   // ushorts per LDS row: 32 + 8 pad

template<int MODE>
__global__ __launch_bounds__(256)
void gemm_kernel(const ushort_t* __restrict__ A, const ushort_t* __restrict__ Bt,
                 ushort_t* __restrict__ o16a, ushort_t* __restrict__ o16b,
                 float* __restrict__ o32)
{
    __shared__ ushort_t ldsA[128 * LDK];
    __shared__ ushort_t ldsB[128 * LDK];

    const int tid = threadIdx.x;
    const int n0 = blockIdx.x * 128, m0 = blockIdx.y * 128;
    const int w = tid >> 6, l = tid & 63, g = l >> 4, c = l & 15;
    const int wm = w >> 1, wn = w & 1;

    const int srow = tid >> 2, skc = tid & 3;
    const ushort_t* ag0 = A  + (size_t)(m0 + srow)      * 1024 + skc * 8;
    const ushort_t* ag1 = A  + (size_t)(m0 + srow + 64) * 1024 + skc * 8;
    const ushort_t* bg0 = Bt + (size_t)(n0 + srow)      * 1024 + skc * 8;
    const ushort_t* bg1 = Bt + (size_t)(n0 + srow + 64) * 1024 + skc * 8;
    const int l0 = srow * LDK + skc * 8;
    const int l1 = (srow + 64) * LDK + skc * 8;

    f32x4 acc[4][4];
    #pragma unroll
    for (int mi = 0; mi < 4; ++mi)
        #pragma unroll
        for (int ni = 0; ni < 4; ++ni)
            acc[mi][ni] = (f32x4){0.f, 0.f, 0.f, 0.f};

    for (int kt = 0; kt < 32; ++kt) {
        const int ko = kt * 32;
        uint4 a0 = *reinterpret_cast<const uint4*>(ag0 + ko);
        uint4 a1 = *reinterpret_cast<const uint4*>(ag1 + ko);
        uint4 b0 = *reinterpret_cast<const uint4*>(bg0 + ko);
        uint4 b1 = *reinterpret_cast<const uint4*>(bg1 + ko);
        __syncthreads();
        *reinterpret_cast<uint4*>(&ldsA[l0]) = a0;
        *reinterpret_cast<uint4*>(&ldsA[l1]) = a1;
        *reinterpret_cast<uint4*>(&ldsB[l0]) = b0;
        *reinterpret_cast<uint4*>(&ldsB[l1]) = b1;
        __syncthreads();

        Frag af[4], bfr[4];
        #pragma unroll
        for (int mi = 0; mi < 4; ++mi)
            af[mi].u4 = *reinterpret_cast<const uint4*>(&ldsA[(wm * 64 + mi * 16 + c) * LDK + g * 8]);
        #pragma unroll
        for (int ni = 0; ni < 4; ++ni)
            bfr[ni].u4 = *reinterpret_cast<const uint4*>(&ldsB[(wn * 64 + ni * 16 + c) * LDK + g * 8]);
        #pragma unroll
        for (int mi = 0; mi < 4; ++mi)
            #pragma unroll
            for (int ni = 0; ni < 4; ++ni)
                acc[mi][ni] = __builtin_amdgcn_mfma_f32_16x16x32_bf16(
                    af[mi].b, bfr[ni].b, acc[mi][ni], 0, 0, 0);
    }

    #pragma unroll
    for (int mi = 0; mi < 4; ++mi) {
        const int mbase = m0 + wm * 64 + mi * 16 + g * 4;
        #pragma unroll
        for (int ni = 0; ni < 4; ++ni) {
            const int n = n0 + wn * 64 + ni * 16 + c;
            if (MODE == 0) {
                const int hh = n >> 6, d = n & 63;
                #pragma unroll
                for (int r = 0; r < 4; ++r) {
                    const int m = mbase + r;
                    const int b = m >> 11, tok = m & 2047;
                    o16a[(((size_t)b * 16 + hh) * 2048 + tok) * 64 + d] =
                        f2bf(acc[mi][ni][r] * 0.125f);
                }
            } else if (MODE == 1) {
                if (n < 1024) {
                    const int hh = n >> 6, d = n & 63;
                    #pragma unroll
                    for (int r = 0; r < 4; ++r) {
                        const int m = mbase + r;
                        const int b = m >> 11, tok = m & 2047;
                        o16a[(((size_t)b * 16 + hh) * 2048 + tok) * 64 + d] =
                            f2bf(acc[mi][ni][r]);
                    }
                } else {
                    const int nn = n - 1024;
                    const int hh = nn >> 6, d = nn & 63;
                    const int b = mbase >> 11, tok0 = mbase & 2047;
                    ushort4 pv;
                    pv.x = f2bf(acc[mi][ni][0]);
                    pv.y = f2bf(acc[mi][ni][1]);
                    pv.z = f2bf(acc[mi][ni][2]);
                    pv.w = f2bf(acc[mi][ni][3]);
                    *reinterpret_cast<ushort4*>(
                        o16b + (((size_t)b * 16 + hh) * 64 + d) * 2048 + tok0) = pv;
                }
            } else {
                #pragma unroll
                for (int r = 0; r < 4; ++r)
                    o32[(size_t)(mbase + r) * 1024 + n] = acc[mi][ni][r];
            }
        }
    }
}

// ---------------------------------------------------------------- flash attention v3
// grid (16 qblocks, 64 bh); 8 waves/block, wave owns 16 q-rows (block = 128 rows).
// K and V tiles (KVBLK=64) LDS-staged once per block via global_load_lds,
// double-buffered, XOR-swizzled (linear dest + inverse-swizzled SOURCE + swizzled
// READ per rule 21). Swapped QK^T keeps softmax in-lane; defer-max (T13).
__global__ __launch_bounds__(512)
void attn_kernel(const ushort_t* __restrict__ q, const ushort_t* __restrict__ k,
                 const ushort_t* __restrict__ vt, const float* __restrict__ nkv,
                 ushort_t* __restrict__ out)
{
    // per buffer: K tile [64 kv][8 granules of 8 ushorts] then V tile [64 d][8 gr]
    __shared__ ushort_t kvs[2][8192];        // 2 x 16 KB
    __shared__ ushort_t plds[8][16 * 72];    // per-wave P buffer [q=16][kv=64+8pad]

    const int tid = threadIdx.x;
    const int w = tid >> 6, l = tid & 63, g = l >> 4, c = l & 15;
    const int qb = blockIdx.x, bh = blockIdx.y, h = bh & 15;

    const ushort_t* kb = k  + (size_t)bh * 2048 * 64;
    const ushort_t* vb = vt + (size_t)bh * 64 * 2048;

    // staging geometry: granule n = tid for K and for V (512 granules each);
    // LDS slot (row, s) holds logical granule s ^ (row&7)  -> source pre-swizzle
    const int srow = tid >> 3;                       // 0..63
    const int ssl  = (tid & 7) ^ (srow & 7);         // inverse-swizzled source slot
    const ushort_t* ksrc = kb + srow * 64 + ssl * 8; // + t*4096
    const ushort_t* vsrc = vb + srow * 2048 + ssl * 8; // + t*64

    // Q fragments: lane holds Q[row=c][d = kk*32 + g*8 + i]  (q pre-scaled by 0.125)
    const ushort_t* qbase = q + ((size_t)bh * 2048 + qb * 128 + w * 16) * 64;
    Frag aq[2];
    #pragma unroll
    for (int kk = 0; kk < 2; ++kk)
        aq[kk].u4 = *reinterpret_cast<const uint4*>(qbase + c * 64 + kk * 32 + g * 8);

    // snull = q_row(c) . null_k  — reduce across the 4 g-copies
    float snull = 0.f;
    #pragma unroll
    for (int kk = 0; kk < 2; ++kk) {
        const float4 n0 = *reinterpret_cast<const float4*>(nkv + h * 64 + kk * 32 + g * 8);
        const float4 n1 = *reinterpret_cast<const float4*>(nkv + h * 64 + kk * 32 + g * 8 + 4);
        snull += bf2f(aq[kk].s[0]) * n0.x + bf2f(aq[kk].s[1]) * n0.y
               + bf2f(aq[kk].s[2]) * n0.z + bf2f(aq[kk].s[3]) * n0.w;
        snull += bf2f(aq[kk].s[4]) * n1.x + bf2f(aq[kk].s[5]) * n1.y
               + bf2f(aq[kk].s[6]) * n1.z + bf2f(aq[kk].s[7]) * n1.w;
    }
    snull += __shfl_xor(snull, 16);
    snull += __shfl_xor(snull, 32);

    float m_run = snull;     // per-lane state for q-row = c
    float l_run = 1.f;

    f32x4 acc[4];            // O[q = g*4+r][d = nf*16+c] ; init with null_v
    #pragma unroll
    for (int nf = 0; nf < 4; ++nf) {
        const float nv = nkv[1024 + h * 64 + nf * 16 + c];
        #pragma unroll
        for (int r = 0; r < 4; ++r) acc[nf][r] = nv;
    }

    ushort_t* pw = &plds[w][0];
    const int swz = c & 7;   // read-side XOR

    // prologue: stage tile 0 into buf 0
    __builtin_amdgcn_global_load_lds((gvoid_t*)(ksrc), (svoid_t*)(&kvs[0][tid * 8]), 16, 0, 0);
    __builtin_amdgcn_global_load_lds((gvoid_t*)(vsrc), (svoid_t*)(&kvs[0][4096 + tid * 8]), 16, 0, 0);
    __syncthreads();

    int cur = 0;
    for (int t = 0; t < 32; ++t) {
        if (t < 31) {   // stage next tile into the other buffer
            __builtin_amdgcn_global_load_lds((gvoid_t*)(ksrc + (t + 1) * 4096),
                                             (svoid_t*)(&kvs[cur ^ 1][tid * 8]), 16, 0, 0);
            __builtin_amdgcn_global_load_lds((gvoid_t*)(vsrc + (t + 1) * 64),
                                             (svoid_t*)(&kvs[cur ^ 1][4096 + tid * 8]), 16, 0, 0);
        }
        const ushort_t* kbuf = &kvs[cur][0];
        const ushort_t* vbuf = &kvs[cur][4096];

        // K as A-fragment from LDS (swizzled read):
        // lane holds K[kv_local = nt*16 + c][d = kk*32 + g*8 + i]
        Frag bk[4][2];
        #pragma unroll
        for (int nt = 0; nt < 4; ++nt)
            #pragma unroll
            for (int kk = 0; kk < 2; ++kk)
                bk[nt][kk].u4 = *reinterpret_cast<const uint4*>(
                    &kbuf[(nt * 16 + c) * 64 + (((kk << 2) | g) ^ swz) * 8]);

        // S^T[kv][q]: lane holds q = c, kv_local = nt*16 + g*4 + r
        f32x4 st[4];
        #pragma unroll
        for (int nt = 0; nt < 4; ++nt) {
            f32x4 z = (f32x4){0.f, 0.f, 0.f, 0.f};
            st[nt] = __builtin_amdgcn_mfma_f32_16x16x32_bf16(bk[nt][0].b, aq[0].b, z, 0, 0, 0);
            st[nt] = __builtin_amdgcn_mfma_f32_16x16x32_bf16(bk[nt][1].b, aq[1].b, st[nt], 0, 0, 0);
        }

        // V fragments from LDS (swizzled) — issue before softmax to hide lgkm
        // lane holds V[kv = k2*32+g*8+i][d = nf*16+c]
        Frag bv[4][2];
        #pragma unroll
        for (int nf = 0; nf < 4; ++nf)
            #pragma unroll
            for (int k2 = 0; k2 < 2; ++k2)
                bv[nf][k2].u4 = *reinterpret_cast<const uint4*>(
                    &vbuf[(nf * 16 + c) * 64 + (((k2 << 2) | g) ^ swz) * 8]);

        // ---- softmax, in-lane for q-row c ----
        float m01 = fmaxf(fmaxf(st[0][0], st[0][1]), fmaxf(st[0][2], st[0][3]));
        float m23 = fmaxf(fmaxf(st[1][0], st[1][1]), fmaxf(st[1][2], st[1][3]));
        float m45 = fmaxf(fmaxf(st[2][0], st[2][1]), fmaxf(st[2][2], st[2][3]));
        float m67 = fmaxf(fmaxf(st[3][0], st[3][1]), fmaxf(st[3][2], st[3][3]));
        float pm = fmaxf(fmaxf(m01, m23), fmaxf(m45, m67));
        pm = fmaxf(pm, __shfl_xor(pm, 16));
        pm = fmaxf(pm, __shfl_xor(pm, 32));

        if (__any(pm > m_run + 8.f)) {      // T13 defer-max
            const float nm = fmaxf(m_run, pm);
            const float alpha = __expf(m_run - nm);
            m_run = nm;
            l_run *= alpha;
            float av[4];
            #pragma unroll
            for (int r = 0; r < 4; ++r) av[r] = __shfl(alpha, g * 4 + r);
            #pragma unroll
            for (int nf = 0; nf < 4; ++nf)
                #pragma unroll
                for (int r = 0; r < 4; ++r)
                    acc[nf][r] *= av[r];
        }

        #pragma unroll
        for (int nt = 0; nt < 4; ++nt)
            #pragma unroll
            for (int r = 0; r < 4; ++r)
                st[nt][r] = __expf(st[nt][r] - m_run);

        float s0 = (st[0][0] + st[0][1]) + (st[0][2] + st[0][3]);
        float s1 = (st[1][0] + st[1][1]) + (st[1][2] + st[1][3]);
        float s2 = (st[2][0] + st[2][1]) + (st[2][2] + st[2][3]);
        float s3 = (st[3][0] + st[3][1]) + (st[3][2] + st[3][3]);
        float ts = (s0 + s1) + (s2 + s3);
        ts += __shfl_xor(ts, 16);
        ts += __shfl_xor(ts, 32);
        l_run += ts;

        // ---- P -> LDS rows [q=c][kv], packed pairs (8x ds_write_b32) ----
        #pragma unroll
        for (int nt = 0; nt < 4; ++nt)
            #pragma unroll
            for (int j = 0; j < 2; ++j)
                *reinterpret_cast<unsigned*>(&pw[c * 72 + nt * 16 + g * 4 + 2 * j]) =
                    pack2bf(st[nt][2 * j], st[nt][2 * j + 1]);

        Frag pa[2];
        #pragma unroll
        for (int k2 = 0; k2 < 2; ++k2)
            pa[k2].u4 = *reinterpret_cast<const uint4*>(&pw[c * 72 + k2 * 32 + g * 8]);

        #pragma unroll
        for (int nf = 0; nf < 4; ++nf) {
            acc[nf] = __builtin_amdgcn_mfma_f32_16x16x32_bf16(pa[0].b, bv[nf][0].b, acc[nf], 0, 0, 0);
            acc[nf] = __builtin_amdgcn_mfma_f32_16x16x32_bf16(pa[1].b, bv[nf][1].b, acc[nf], 0, 0, 0);
        }

        __syncthreads();   // drains vmcnt (stage t+1 done) + lgkm; guards buffer swap
        cur ^= 1;
    }

    // normalize + store: O rows q = g*4+r need 1/l from lane (q)
    const size_t ob = ((size_t)(bh >> 4) * 2048 + qb * 128 + w * 16) * 1024 + h * 64;
    #pragma unroll
    for (int r = 0; r < 4; ++r) {
        const float inv = 1.f / __shfl(l_run, g * 4 + r);
        #pragma unroll
        for (int nf = 0; nf < 4; ++nf)
            out[ob + (size_t)(g * 4 + r) * 1024 + nf * 16 + c] = f2bf(acc[nf][r] * inv);
    }
}

// ---------------------------------------------------------------- launch
extern "C" void kernel_launch(void* const* d_in, const int* in_sizes, int n_in,
                              void* d_out, int out_size, void* d_ws, size_t ws_size,
                              hipStream_t stream)
{
    (void)in_sizes; (void)n_in; (void)out_size; (void)ws_size;
    const float* x     = (const float*)d_in[0];
    const float* gamma = (const float*)d_in[1];
    const float* w_q   = (const float*)d_in[2];
    const float* w_kv  = (const float*)d_in[3];
    const float* w_out = (const float*)d_in[4];
    const float* nkv   = (const float*)d_in[5];
    float* out = (float*)d_out;

    char* ws = (char*)d_ws;
    ushort_t* xn   = (ushort_t*)(ws);               // 16 MB  [8192,1024] bf16
    ushort_t* wqT  = (ushort_t*)(ws + 16777216);    //  2 MB  [1024,1024]
    ushort_t* wkvT = (ushort_t*)(ws + 18874368);    //  4 MB  [2048,1024]
    ushort_t* woT  = (ushort_t*)(ws + 23068672);    //  2 MB  [1024,1024]
    ushort_t* qh   = (ushort_t*)(ws + 25165824);    // 16 MB  [b,h,2048,64]
    ushort_t* kh   = (ushort_t*)(ws + 41943040);    // 16 MB  [b,h,2048,64]
    ushort_t* vtb  = (ushort_t*)(ws + 58720256);    // 16 MB  [b,h,64,2048]
    ushort_t* ao   = xn;                            // attn output reuses xn

    ln_kernel<<<dim3(8192), dim3(256), 0, stream>>>(x, gamma, xn);
    wt_kernel<<<dim3(32, 32), dim3(32, 8), 0, stream>>>(w_q,  wqT, 1024, 1024);
    wt_kernel<<<dim3(64, 32), dim3(32, 8), 0, stream>>>(w_kv, wkvT, 1024, 2048);
    wt_kernel<<<dim3(32, 32), dim3(32, 8), 0, stream>>>(w_out, woT, 1024, 1024);

    gemm_kernel<0><<<dim3(8, 64),  dim3(256), 0, stream>>>(xn, wqT,  qh, nullptr, nullptr);
    gemm_kernel<1><<<dim3(16, 64), dim3(256), 0, stream>>>(xn, wkvT, kh, vtb, nullptr);

    attn_kernel<<<dim3(16, 64), dim3(512), 0, stream>>>(qh, kh, vtb, nkv, ao);

    gemm_kernel<2><<<dim3(8, 64), dim3(256), 0, stream>>>(ao, woT, nullptr, nullptr, out);
}

// Round 4
// 245.887 us; speedup vs baseline: 2.3903x; 1.0492x over previous
//
#include <hip/hip_runtime.h>

typedef unsigned short ushort_t;
using f32x4  = __attribute__((ext_vector_type(4))) float;
using bf16x8 = __attribute__((ext_vector_type(8))) __bf16;

typedef __attribute__((address_space(1))) const void gvoid_t;
typedef __attribute__((address_space(3))) void svoid_t;

union Frag {
    uint4    u4;
    bf16x8   b;
    ushort_t s[8];
};

__device__ __forceinline__ ushort_t f2bf(float f) {
    union { float f; unsigned u; } a; a.f = f;
    unsigned u = a.u;
    unsigned r = (u + 0x7fffu + ((u >> 16) & 1u)) >> 16;   // RNE
    return (ushort_t)r;
}
__device__ __forceinline__ float bf2f(ushort_t b) {
    union { unsigned u; float f; } a; a.u = ((unsigned)b) << 16;
    return a.f;
}
__device__ __forceinline__ unsigned pack2bf(float lo, float hi) {
    union { __bf16 h[2]; unsigned u; } p;
    p.h[0] = (__bf16)lo;
    p.h[1] = (__bf16)hi;
    return p.u;
}

// ---------------------------------------------------------------- LayerNorm
__global__ __launch_bounds__(256)
void ln_kernel(const float* __restrict__ x, const float* __restrict__ gamma,
               ushort_t* __restrict__ xn)
{
    const int row = blockIdx.x;
    const int tid = threadIdx.x;
    const float4 v = *reinterpret_cast<const float4*>(x + (size_t)row * 1024 + tid * 4);

    float s = v.x + v.y + v.z + v.w;
    float q = v.x * v.x + v.y * v.y + v.z * v.z + v.w * v.w;
    #pragma unroll
    for (int off = 1; off <= 32; off <<= 1) {
        s += __shfl_xor(s, off);
        q += __shfl_xor(q, off);
    }
    __shared__ float ss[4], sq[4];
    if ((tid & 63) == 0) { ss[tid >> 6] = s; sq[tid >> 6] = q; }
    __syncthreads();
    const float S  = ss[0] + ss[1] + ss[2] + ss[3];
    const float Q  = sq[0] + sq[1] + sq[2] + sq[3];
    const float mu = S * (1.0f / 1024.0f);
    const float var = Q * (1.0f / 1024.0f) - mu * mu;
    const float rstd = rsqrtf(var + 1e-5f);

    const float4 gm = *reinterpret_cast<const float4*>(gamma + tid * 4);
    ushort4 o;
    o.x = f2bf((v.x - mu) * rstd * gm.x);
    o.y = f2bf((v.y - mu) * rstd * gm.y);
    o.z = f2bf((v.z - mu) * rstd * gm.z);
    o.w = f2bf((v.w - mu) * rstd * gm.w);
    *reinterpret_cast<ushort4*>(xn + (size_t)row * 1024 + tid * 4) = o;
}

// ------------------------------------------- weight transpose fp32[K][N] -> bf16[N][K]
__global__ __launch_bounds__(256)
void wt_kernel(const float* __restrict__ w, ushort_t* __restrict__ wt, int K, int N)
{
    __shared__ float tile[32][33];
    const int n0 = blockIdx.x * 32, k0 = blockIdx.y * 32;
    const int tx = threadIdx.x, ty = threadIdx.y;   // (32, 8)
    #pragma unroll
    for (int i = 0; i < 4; ++i) {
        int r = ty + i * 8;
        tile[r][tx] = w[(size_t)(k0 + r) * N + n0 + tx];
    }
    __syncthreads();
    #pragma unroll
    for (int i = 0; i < 4; ++i) {
        int r = ty + i * 8;
        wt[(size_t)(n0 + r) * K + k0 + tx] = f2bf(tile[tx][r]);
    }
}

// ---------------------------------------------------------------- GEMM v2 (m97-style)
// C[M,N] = A[M,1024](bf16) * Bt[N,1024](bf16)^T ; 128x128 tile, BK=64, 4 waves.
// global_load_lds width-16 staging; linear LDS dest, inverse-swizzled SOURCE,
// XOR-swizzled ds_read_b128 (slot ^= row&7) -> conflict-free fragment reads.
template<int MODE>
__global__ __launch_bounds__(256)
void gemm_kernel(const ushort_t* __restrict__ A, const ushort_t* __restrict__ Bt,
                 ushort_t* __restrict__ o16a, ushort_t* __restrict__ o16b,
                 float* __restrict__ o32)
{
    __shared__ ushort_t ldsA[128 * 64];   // 16 KB, rows of 8 granules (16 B each)
    __shared__ ushort_t ldsB[128 * 64];

    const int tid = threadIdx.x;
    const int n0 = blockIdx.x * 128, m0 = blockIdx.y * 128;
    const int w = tid >> 6, l = tid & 63, g = l >> 4, c = l & 15;
    const int wm = w >> 1, wn = w & 1;

    // staging: granule gidx = j*256 + tid ; row = gidx>>3, phys slot = gidx&7
    // LDS slot s holds logical granule s ^ (row&7)  (source pre-swizzle)
    const ushort_t* asrc[4];
    const ushort_t* bsrc[4];
    #pragma unroll
    for (int j = 0; j < 4; ++j) {
        const int gidx = j * 256 + tid;
        const int row = gidx >> 3;
        const int sl  = (gidx & 7) ^ (row & 7);
        asrc[j] = A  + (size_t)(m0 + row) * 1024 + sl * 8;
        bsrc[j] = Bt + (size_t)(n0 + row) * 1024 + sl * 8;
    }

    f32x4 acc[4][4];
    #pragma unroll
    for (int mi = 0; mi < 4; ++mi)
        #pragma unroll
        for (int ni = 0; ni < 4; ++ni)
            acc[mi][ni] = (f32x4){0.f, 0.f, 0.f, 0.f};

    const int swz = c & 7;

    for (int kt = 0; kt < 16; ++kt) {
        if (kt) __syncthreads();     // prev tile's reads complete before overwrite
        #pragma unroll
        for (int j = 0; j < 4; ++j) {
            __builtin_amdgcn_global_load_lds((gvoid_t*)(asrc[j] + kt * 64),
                                             (svoid_t*)(&ldsA[(j * 256 + tid) * 8]), 16, 0, 0);
            __builtin_amdgcn_global_load_lds((gvoid_t*)(bsrc[j] + kt * 64),
                                             (svoid_t*)(&ldsB[(j * 256 + tid) * 8]), 16, 0, 0);
        }
        __syncthreads();             // implicit vmcnt(0) drain -> staging visible

        #pragma unroll
        for (int kk = 0; kk < 2; ++kk) {
            Frag af[4], bfr[4];
            #pragma unroll
            for (int mi = 0; mi < 4; ++mi)
                af[mi].u4 = *reinterpret_cast<const uint4*>(
                    &ldsA[(wm * 64 + mi * 16 + c) * 64 + ((((kk << 2) | g)) ^ swz) * 8]);
            #pragma unroll
            for (int ni = 0; ni < 4; ++ni)
                bfr[ni].u4 = *reinterpret_cast<const uint4*>(
                    &ldsB[(wn * 64 + ni * 16 + c) * 64 + ((((kk << 2) | g)) ^ swz) * 8]);
            #pragma unroll
            for (int mi = 0; mi < 4; ++mi)
                #pragma unroll
                for (int ni = 0; ni < 4; ++ni)
                    acc[mi][ni] = __builtin_amdgcn_mfma_f32_16x16x32_bf16(
                        af[mi].b, bfr[ni].b, acc[mi][ni], 0, 0, 0);
        }
    }

    // epilogue:  rows m = mbase + r, col n;  D layout: row=(l>>4)*4+r, col=l&15
    #pragma unroll
    for (int mi = 0; mi < 4; ++mi) {
        const int mbase = m0 + wm * 64 + mi * 16 + g * 4;
        #pragma unroll
        for (int ni = 0; ni < 4; ++ni) {
            const int n = n0 + wn * 64 + ni * 16 + c;
            if (MODE == 0) {
                const int hh = n >> 6, d = n & 63;
                #pragma unroll
                for (int r = 0; r < 4; ++r) {
                    const int m = mbase + r;
                    const int b = m >> 11, tok = m & 2047;
                    o16a[(((size_t)b * 16 + hh) * 2048 + tok) * 64 + d] =
                        f2bf(acc[mi][ni][r] * 0.125f);
                }
            } else if (MODE == 1) {
                if (n < 1024) {
                    const int hh = n >> 6, d = n & 63;
                    #pragma unroll
                    for (int r = 0; r < 4; ++r) {
                        const int m = mbase + r;
                        const int b = m >> 11, tok = m & 2047;
                        o16a[(((size_t)b * 16 + hh) * 2048 + tok) * 64 + d] =
                            f2bf(acc[mi][ni][r]);
                    }
                } else {
                    const int nn = n - 1024;
                    const int hh = nn >> 6, d = nn & 63;
                    const int b = mbase >> 11, tok0 = mbase & 2047;
                    ushort4 pv;
                    pv.x = f2bf(acc[mi][ni][0]);
                    pv.y = f2bf(acc[mi][ni][1]);
                    pv.z = f2bf(acc[mi][ni][2]);
                    pv.w = f2bf(acc[mi][ni][3]);
                    *reinterpret_cast<ushort4*>(
                        o16b + (((size_t)b * 16 + hh) * 64 + d) * 2048 + tok0) = pv;
                }
            } else {
                #pragma unroll
                for (int r = 0; r < 4; ++r)
                    o32[(size_t)(mbase + r) * 1024 + n] = acc[mi][ni][r];
            }
        }
    }
}

// ---------------------------------------------------------------- flash attention v4
// grid (16 qblocks, 64 bh); 8 waves/block, wave owns 16 q-rows (block = 128 rows).
// K/V LDS-staged (global_load_lds, double-buffered, XOR-swizzled). Swapped QK^T,
// in-lane softmax, defer-max (T13), deferred l-reduction, setprio (T5),
// XOR-swizzled no-pad P buffer (b64 writes / b128 reads at uniform bank minimum).
__global__ __launch_bounds__(512)
void attn_kernel(const ushort_t* __restrict__ q, const ushort_t* __restrict__ k,
                 const ushort_t* __restrict__ vt, const float* __restrict__ nkv,
                 ushort_t* __restrict__ out)
{
    __shared__ ushort_t kvs[2][8192];        // 2 x 16 KB (K tile 8 KB + V tile 8 KB)
    __shared__ unsigned plds[8][16 * 32];    // per-wave P buffer, u32 words, no pad

    const int tid = threadIdx.x;
    const int w = tid >> 6, l = tid & 63, g = l >> 4, c = l & 15;
    const int qb = blockIdx.x, bh = blockIdx.y, h = bh & 15;

    const ushort_t* kb = k  + (size_t)bh * 2048 * 64;
    const ushort_t* vb = vt + (size_t)bh * 64 * 2048;

    // staging geometry: LDS slot (row, s) holds logical granule s ^ (row&7)
    const int srow = tid >> 3;                         // 0..63
    const int ssl  = (tid & 7) ^ (srow & 7);
    const ushort_t* ksrc = kb + srow * 64 + ssl * 8;   // + t*4096
    const ushort_t* vsrc = vb + srow * 2048 + ssl * 8; // + t*64

    // Q fragments: lane holds Q[row=c][d = kk*32 + g*8 + i]  (q pre-scaled by 0.125)
    const ushort_t* qbase = q + ((size_t)bh * 2048 + qb * 128 + w * 16) * 64;
    Frag aq[2];
    #pragma unroll
    for (int kk = 0; kk < 2; ++kk)
        aq[kk].u4 = *reinterpret_cast<const uint4*>(qbase + c * 64 + kk * 32 + g * 8);

    // snull = q_row(c) . null_k
    float snull = 0.f;
    #pragma unroll
    for (int kk = 0; kk < 2; ++kk) {
        const float4 n0 = *reinterpret_cast<const float4*>(nkv + h * 64 + kk * 32 + g * 8);
        const float4 n1 = *reinterpret_cast<const float4*>(nkv + h * 64 + kk * 32 + g * 8 + 4);
        snull += bf2f(aq[kk].s[0]) * n0.x + bf2f(aq[kk].s[1]) * n0.y
               + bf2f(aq[kk].s[2]) * n0.z + bf2f(aq[kk].s[3]) * n0.w;
        snull += bf2f(aq[kk].s[4]) * n1.x + bf2f(aq[kk].s[5]) * n1.y
               + bf2f(aq[kk].s[6]) * n1.z + bf2f(aq[kk].s[7]) * n1.w;
    }
    snull += __shfl_xor(snull, 16);
    snull += __shfl_xor(snull, 32);

    float m_run  = snull;                 // per-lane state for q-row = c
    float l_part = (l < 16) ? 1.f : 0.f;  // deferred-l: per-lane partial sum

    f32x4 acc[4];            // O[q = g*4+r][d = nf*16+c] ; init with null_v
    #pragma unroll
    for (int nf = 0; nf < 4; ++nf) {
        const float nv = nkv[1024 + h * 64 + nf * 16 + c];
        #pragma unroll
        for (int r = 0; r < 4; ++r) acc[nf][r] = nv;
    }

    unsigned* pw = &plds[w][0] + c * 32;
    const int swz  = c & 7;          // K/V read-side XOR (granule index)
    const int swzP = (c & 7) << 2;   // P-buffer XOR (u32-word index)

    // prologue: stage tile 0 into buf 0
    __builtin_amdgcn_global_load_lds((gvoid_t*)(ksrc), (svoid_t*)(&kvs[0][tid * 8]), 16, 0, 0);
    __builtin_amdgcn_global_load_lds((gvoid_t*)(vsrc), (svoid_t*)(&kvs[0][4096 + tid * 8]), 16, 0, 0);
    __syncthreads();

    int cur = 0;
    for (int t = 0; t < 32; ++t) {
        if (t < 31) {
            __builtin_amdgcn_global_load_lds((gvoid_t*)(ksrc + (t + 1) * 4096),
                                             (svoid_t*)(&kvs[cur ^ 1][tid * 8]), 16, 0, 0);
            __builtin_amdgcn_global_load_lds((gvoid_t*)(vsrc + (t + 1) * 64),
                                             (svoid_t*)(&kvs[cur ^ 1][4096 + tid * 8]), 16, 0, 0);
        }
        const ushort_t* kbuf = &kvs[cur][0];
        const ushort_t* vbuf = &kvs[cur][4096];

        // K as A-fragment (swizzled LDS read)
        Frag bk[4][2];
        #pragma unroll
        for (int nt = 0; nt < 4; ++nt)
            #pragma unroll
            for (int kk = 0; kk < 2; ++kk)
                bk[nt][kk].u4 = *reinterpret_cast<const uint4*>(
                    &kbuf[(nt * 16 + c) * 64 + (((kk << 2) | g) ^ swz) * 8]);

        // S^T[kv][q]: lane holds q = c, kv_local = nt*16 + g*4 + r
        f32x4 st[4];
        __builtin_amdgcn_s_setprio(1);
        #pragma unroll
        for (int nt = 0; nt < 4; ++nt) {
            f32x4 z = (f32x4){0.f, 0.f, 0.f, 0.f};
            st[nt] = __builtin_amdgcn_mfma_f32_16x16x32_bf16(bk[nt][0].b, aq[0].b, z, 0, 0, 0);
            st[nt] = __builtin_amdgcn_mfma_f32_16x16x32_bf16(bk[nt][1].b, aq[1].b, st[nt], 0, 0, 0);
        }
        __builtin_amdgcn_s_setprio(0);

        // V fragments (issue before softmax to hide lgkm latency)
        Frag bv[4][2];
        #pragma unroll
        for (int nf = 0; nf < 4; ++nf)
            #pragma unroll
            for (int k2 = 0; k2 < 2; ++k2)
                bv[nf][k2].u4 = *reinterpret_cast<const uint4*>(
                    &vbuf[(nf * 16 + c) * 64 + (((k2 << 2) | g) ^ swz) * 8]);

        // ---- softmax, in-lane for q-row c ----
        float m01 = fmaxf(fmaxf(st[0][0], st[0][1]), fmaxf(st[0][2], st[0][3]));
        float m23 = fmaxf(fmaxf(st[1][0], st[1][1]), fmaxf(st[1][2], st[1][3]));
        float m45 = fmaxf(fmaxf(st[2][0], st[2][1]), fmaxf(st[2][2], st[2][3]));
        float m67 = fmaxf(fmaxf(st[3][0], st[3][1]), fmaxf(st[3][2], st[3][3]));
        float pm = fmaxf(fmaxf(m01, m23), fmaxf(m45, m67));
        pm = fmaxf(pm, __shfl_xor(pm, 16));
        pm = fmaxf(pm, __shfl_xor(pm, 32));

        if (__any(pm > m_run + 8.f)) {      // T13 defer-max
            const float nm = fmaxf(m_run, pm);
            const float alpha = __expf(m_run - nm);
            m_run = nm;
            l_part *= alpha;
            float av[4];
            #pragma unroll
            for (int r = 0; r < 4; ++r) av[r] = __shfl(alpha, g * 4 + r);
            #pragma unroll
            for (int nf = 0; nf < 4; ++nf)
                #pragma unroll
                for (int r = 0; r < 4; ++r)
                    acc[nf][r] *= av[r];
        }

        #pragma unroll
        for (int nt = 0; nt < 4; ++nt)
            #pragma unroll
            for (int r = 0; r < 4; ++r)
                st[nt][r] = __expf(st[nt][r] - m_run);

        float s0 = (st[0][0] + st[0][1]) + (st[0][2] + st[0][3]);
        float s1 = (st[1][0] + st[1][1]) + (st[1][2] + st[1][3]);
        float s2 = (st[2][0] + st[2][1]) + (st[2][2] + st[2][3]);
        float s3 = (st[3][0] + st[3][1]) + (st[3][2] + st[3][3]);
        l_part += (s0 + s1) + (s2 + s3);    // deferred: no cross-lane reduce here

        // ---- P -> LDS, swizzled b64 writes: phys word = logical ^ swzP ----
        #pragma unroll
        for (int nt = 0; nt < 4; ++nt) {
            uint2 pr;
            pr.x = pack2bf(st[nt][0], st[nt][1]);
            pr.y = pack2bf(st[nt][2], st[nt][3]);
            *reinterpret_cast<uint2*>(&pw[(nt * 8 + 2 * g) ^ swzP]) = pr;
        }

        Frag pa[2];
        #pragma unroll
        for (int k2 = 0; k2 < 2; ++k2)
            pa[k2].u4 = *reinterpret_cast<const uint4*>(&pw[(k2 * 16 + 4 * g) ^ swzP]);

        __builtin_amdgcn_s_setprio(1);
        #pragma unroll
        for (int nf = 0; nf < 4; ++nf) {
            acc[nf] = __builtin_amdgcn_mfma_f32_16x16x32_bf16(pa[0].b, bv[nf][0].b, acc[nf], 0, 0, 0);
            acc[nf] = __builtin_amdgcn_mfma_f32_16x16x32_bf16(pa[1].b, bv[nf][1].b, acc[nf], 0, 0, 0);
        }
        __builtin_amdgcn_s_setprio(0);

        __syncthreads();   // drains vmcnt (stage t+1) ; guards buffer swap
        cur ^= 1;
    }

    // final l reduction across the 4 g-copies, then normalize + store
    l_part += __shfl_xor(l_part, 16);
    l_part += __shfl_xor(l_part, 32);

    const size_t ob = ((size_t)(bh >> 4) * 2048 + qb * 128 + w * 16) * 1024 + h * 64;
    #pragma unroll
    for (int r = 0; r < 4; ++r) {
        const float inv = 1.f / __shfl(l_part, g * 4 + r);
        #pragma unroll
        for (int nf = 0; nf < 4; ++nf)
            out[ob + (size_t)(g * 4 + r) * 1024 + nf * 16 + c] = f2bf(acc[nf][r] * inv);
    }
}

// ---------------------------------------------------------------- launch
extern "C" void kernel_launch(void* const* d_in, const int* in_sizes, int n_in,
                              void* d_out, int out_size, void* d_ws, size_t ws_size,
                              hipStream_t stream)
{
    (void)in_sizes; (void)n_in; (void)out_size; (void)ws_size;
    const float* x     = (const float*)d_in[0];
    const float* gamma = (const float*)d_in[1];
    const float* w_q   = (const float*)d_in[2];
    const float* w_kv  = (const float*)d_in[3];
    const float* w_out = (const float*)d_in[4];
    const float* nkv   = (const float*)d_in[5];
    float* out = (float*)d_out;

    char* ws = (char*)d_ws;
    ushort_t* xn   = (ushort_t*)(ws);               // 16 MB  [8192,1024] bf16
    ushort_t* wqT  = (ushort_t*)(ws + 16777216);    //  2 MB  [1024,1024]
    ushort_t* wkvT = (ushort_t*)(ws + 18874368);    //  4 MB  [2048,1024]
    ushort_t* woT  = (ushort_t*)(ws + 23068672);    //  2 MB  [1024,1024]
    ushort_t* qh   = (ushort_t*)(ws + 25165824);    // 16 MB  [b,h,2048,64]
    ushort_t* kh   = (ushort_t*)(ws + 41943040);    // 16 MB  [b,h,2048,64]
    ushort_t* vtb  = (ushort_t*)(ws + 58720256);    // 16 MB  [b,h,64,2048]
    ushort_t* ao   = xn;                            // attn output reuses xn

    ln_kernel<<<dim3(8192), dim3(256), 0, stream>>>(x, gamma, xn);
    wt_kernel<<<dim3(32, 32), dim3(32, 8), 0, stream>>>(w_q,  wqT, 1024, 1024);
    wt_kernel<<<dim3(64, 32), dim3(32, 8), 0, stream>>>(w_kv, wkvT, 1024, 2048);
    wt_kernel<<<dim3(32, 32), dim3(32, 8), 0, stream>>>(w_out, woT, 1024, 1024);

    gemm_kernel<0><<<dim3(8, 64),  dim3(256), 0, stream>>>(xn, wqT,  qh, nullptr, nullptr);
    gemm_kernel<1><<<dim3(16, 64), dim3(256), 0, stream>>>(xn, wkvT, kh, vtb, nullptr);

    attn_kernel<<<dim3(16, 64), dim3(512), 0, stream>>>(qh, kh, vtb, nkv, ao);

    gemm_kernel<2><<<dim3(8, 64), dim3(256), 0, stream>>>(ao, woT, nullptr, nullptr, out);
}